// Round 1
// baseline (220.388 us; speedup 1.0000x reference)
//
#include <hip/hip_runtime.h>

#define CT  0.7f
#define CPT 0.5f
#define BB  32
#define TT  2048
#define DD  512
#define MAXR 1025          // T/2 + 1
#define NSLOTS (BB * MAXR) // 32800

// ws layout: wsF[0]=attn_acc, wsF[1]=feat_acc, wsI[2]=n_qual, desc at byte 16
// desc[slot] = {base, cnt, bits(1/cnt), bits(1/rep_cnt)}; cnt==0 -> invalid

__global__ void k_init(float* wsF) {
    wsF[0] = 0.f; wsF[1] = 0.f; ((int*)wsF)[2] = 0;
}

__global__ __launch_bounds__(256) void k_attn(const float* __restrict__ attn,
                                              int4* __restrict__ desc,
                                              float* wsF, int* wsI) {
    const int row = blockIdx.x;
    const int t = threadIdx.x;

    __shared__ float s_cnt[MAXR], s_sum[MAXR], s_rep[MAXR], s_mse[MAXR];
    __shared__ int   s_pos[MAXR];
    __shared__ int   s_scan[256];
    __shared__ float s_vid;
    __shared__ int   s_qual;

    for (int r = t; r < MAXR; r += 256) {
        s_cnt[r] = 0.f; s_sum[r] = 0.f; s_rep[r] = 0.f; s_mse[r] = 0.f;
    }
    if (t == 0) { s_vid = 0.f; s_qual = 0; }

    const float* arow = attn + row * TT;
    const float4* a4 = (const float4*)arow;
    float4 v0 = a4[t * 2], v1 = a4[t * 2 + 1];
    float a[8] = {v0.x, v0.y, v0.z, v0.w, v1.x, v1.y, v1.z, v1.w};
    float aprev = (t > 0) ? arow[t * 8 - 1] : 0.f;   // row-local pad: prev=false at p=0

    bool pred[8], start[8];
    bool pv = aprev > CPT;
    int s = 0;
    #pragma unroll
    for (int j = 0; j < 8; j++) {
        pred[j] = a[j] > CPT;
        start[j] = pred[j] && !pv;
        pv = pred[j];
        s += start[j] ? 1 : 0;
    }

    s_scan[t] = s;
    __syncthreads();
    #pragma unroll
    for (int off = 1; off < 256; off <<= 1) {
        int v = s_scan[t];
        if (t >= off) v += s_scan[t - off];
        __syncthreads();
        s_scan[t] = v;
        __syncthreads();
    }
    const int excl = s_scan[t] - s;
    const int nruns = s_scan[255];

    int rid[8];
    int run = excl;
    #pragma unroll
    for (int j = 0; j < 8; j++) {
        if (start[j]) run++;
        rid[j] = run - 1;
        if (pred[j]) {
            atomicAdd(&s_cnt[rid[j]], 1.f);
            atomicAdd(&s_sum[rid[j]], a[j]);
            if (a[j] > CT) atomicAdd(&s_rep[rid[j]], 1.f);
            if (start[j]) s_pos[rid[j]] = t * 8 + j;
        }
    }
    __syncthreads();

    for (int r = t; r < nruns; r += 256) s_sum[r] = s_sum[r] / s_cnt[r];
    __syncthreads();

    #pragma unroll
    for (int j = 0; j < 8; j++) {
        if (pred[j]) {
            float d = a[j] - s_sum[rid[j]];
            atomicAdd(&s_mse[rid[j]], d * d);
        }
    }
    __syncthreads();

    float vid = 0.f; int q = 0;
    for (int r = t; r < MAXR; r += 256) {
        int4 dsc = {0, 0, 0, 0};
        if (r < nruns) {
            float c = s_cnt[r];
            vid += s_mse[r] / c;
            float rc = s_rep[r];
            if (rc > 0.f) {
                q++;
                dsc.x = row * TT + s_pos[r];
                dsc.y = (int)c;
                dsc.z = __float_as_int(1.f / c);
                dsc.w = __float_as_int(1.f / rc);
            }
        }
        desc[row * MAXR + r] = dsc;
    }
    atomicAdd(&s_vid, vid);
    atomicAdd(&s_qual, q);
    __syncthreads();
    if (t == 0) {
        atomicAdd(&wsF[0], s_vid / (float)max(nruns, 1));
        atomicAdd(&wsI[2], s_qual);
    }
}

__global__ __launch_bounds__(256) void k_feat(const float* __restrict__ attn,
                                              const float* __restrict__ feat,
                                              const int4* __restrict__ desc,
                                              float* wsF) {
    __shared__ float bsum;
    if (threadIdx.x == 0) bsum = 0.f;
    __syncthreads();

    const int wave = threadIdx.x >> 6;
    const int lane = threadIdx.x & 63;
    const int slot = blockIdx.x * 4 + wave;

    float s = 0.f;
    bool valid = false;
    if (slot < NSLOTS) {
        int4 d = desc[slot];
        if (d.y > 0) {
            valid = true;
            const float inv_cnt = __int_as_float(d.z);
            const float inv_rep = __int_as_float(d.w);
            float4 acc0 = {0, 0, 0, 0}, acc1 = {0, 0, 0, 0};
            for (int i = 0; i < d.y; i++) {
                const int p = d.x + i;
                const float av = attn[p];
                const float c = inv_cnt - (av > CT ? inv_rep : 0.f);
                const float4* f4 = (const float4*)(feat + (size_t)p * DD);
                float4 x = f4[lane];
                float4 y = f4[lane + 64];
                acc0.x += c * x.x; acc0.y += c * x.y; acc0.z += c * x.z; acc0.w += c * x.w;
                acc1.x += c * y.x; acc1.y += c * y.y; acc1.z += c * y.z; acc1.w += c * y.w;
            }
            s = acc0.x * acc0.x + acc0.y * acc0.y + acc0.z * acc0.z + acc0.w * acc0.w
              + acc1.x * acc1.x + acc1.y * acc1.y + acc1.z * acc1.z + acc1.w * acc1.w;
            #pragma unroll
            for (int off = 32; off >= 1; off >>= 1) s += __shfl_xor(s, off, 64);
        }
    }
    if (valid && lane == 0) atomicAdd(&bsum, s);
    __syncthreads();
    if (threadIdx.x == 0 && bsum != 0.f) atomicAdd(&wsF[1], bsum);
}

__global__ void k_final(const float* wsF, const int* wsI, float* out) {
    float feat_loss = wsF[1] / (float)DD / (float)max(wsI[2], 1);
    float attn_loss = wsF[0] / (float)BB;
    out[0] = feat_loss + attn_loss;
}

extern "C" void kernel_launch(void* const* d_in, const int* in_sizes, int n_in,
                              void* d_out, int out_size, void* d_ws, size_t ws_size,
                              hipStream_t stream) {
    const float* attn = (const float*)d_in[0];
    const float* feat = (const float*)d_in[1];
    float* wsF = (float*)d_ws;
    int*   wsI = (int*)d_ws;
    int4*  desc = (int4*)((char*)d_ws + 16);

    k_init<<<1, 1, 0, stream>>>(wsF);
    k_attn<<<BB, 256, 0, stream>>>(attn, desc, wsF, wsI);
    const int blocks = (NSLOTS + 3) / 4;
    k_feat<<<blocks, 256, 0, stream>>>(attn, feat, desc, wsF);
    k_final<<<1, 1, 0, stream>>>(wsF, wsI, (float*)d_out);
}

// Round 2
// 214.143 us; speedup vs baseline: 1.0292x; 1.0292x over previous
//
#include <hip/hip_runtime.h>

#define CT  0.7f
#define CPT 0.5f
#define BB  32
#define TT  2048
#define DD  512
#define MAXR 1025            // T/2 + 1
#define QCAP (BB * MAXR)
#define K2_BLOCKS 512
#define K2_WAVES  (K2_BLOCKS * 4)

// ws layout (zeroed by hipMemsetAsync, 256 B header):
//   wsF[0] = attn-level accumulator (sum over rows of vid_loss/nruns)
//   wsF[1] = feat-level accumulator (sum of ||feat_mean-rep_mean||^2 * D ... raw sq-sum)
//   wsI[2] = qualified-run queue count (== n_qual)
//   wsI[3] = done-block ticket counter
//   queue  = int4[QCAP] at byte 256: {base_pos, cnt, bits(1/cnt), bits(1/rep_cnt)}

__global__ __launch_bounds__(256) void k_attn(const float* __restrict__ attn,
                                              int4* __restrict__ queue,
                                              float* wsF, int* wsI) {
    const int row  = blockIdx.x;
    const int t    = threadIdx.x;
    const int lane = t & 63;
    const int wv   = t >> 6;

    __shared__ float s_cnt[MAXR], s_sum[MAXR], s_rep[MAXR], s_mse[MAXR];
    __shared__ int   s_pos[MAXR];
    __shared__ int   s_wsum[4];
    __shared__ float s_part[4];

    for (int r = t; r < MAXR; r += 256) {
        s_cnt[r] = 0.f; s_sum[r] = 0.f; s_rep[r] = 0.f; s_mse[r] = 0.f;
    }

    const float* arow = attn + row * TT;
    const float4* a4 = (const float4*)arow;
    float4 v0 = a4[t * 2], v1 = a4[t * 2 + 1];
    float a[8] = {v0.x, v0.y, v0.z, v0.w, v1.x, v1.y, v1.z, v1.w};
    float aprev = (t > 0) ? arow[t * 8 - 1] : 0.f;   // prev=false at row start

    bool pred[8], start[8];
    bool pv = aprev > CPT;
    int s = 0;
    #pragma unroll
    for (int j = 0; j < 8; j++) {
        pred[j]  = a[j] > CPT;
        start[j] = pred[j] && !pv;
        pv = pred[j];
        s += start[j] ? 1 : 0;
    }

    // wave-level inclusive scan of start counts (6 shfl steps), then block combine
    int v = s;
    #pragma unroll
    for (int off = 1; off < 64; off <<= 1) {
        int u = __shfl_up(v, off, 64);
        if (lane >= off) v += u;
    }
    if (lane == 63) s_wsum[wv] = v;
    __syncthreads();   // also orders the LDS array init before atomics below

    int base = 0;
    #pragma unroll
    for (int w = 0; w < 4; w++) base += (w < wv) ? s_wsum[w] : 0;
    const int excl  = base + v - s;
    const int nruns = s_wsum[0] + s_wsum[1] + s_wsum[2] + s_wsum[3];

    int rid[8];
    int run = excl;
    #pragma unroll
    for (int j = 0; j < 8; j++) {
        if (start[j]) run++;
        rid[j] = run - 1;
        if (pred[j]) {
            atomicAdd(&s_cnt[rid[j]], 1.f);
            atomicAdd(&s_sum[rid[j]], a[j]);
            if (a[j] > CT) atomicAdd(&s_rep[rid[j]], 1.f);
            if (start[j]) s_pos[rid[j]] = t * 8 + j;
        }
    }
    __syncthreads();

    for (int r = t; r < nruns; r += 256) s_sum[r] = s_sum[r] / s_cnt[r];
    __syncthreads();

    #pragma unroll
    for (int j = 0; j < 8; j++) {
        if (pred[j]) {
            float d = a[j] - s_sum[rid[j]];
            atomicAdd(&s_mse[rid[j]], d * d);
        }
    }
    __syncthreads();

    // per-run wrap-up: attn-level MSE + append qualified runs to global queue
    float vid = 0.f;
    for (int r = t; r < nruns; r += 256) {
        const float c = s_cnt[r];
        vid += s_mse[r] / c;
        const float rc = s_rep[r];
        if (rc > 0.f) {
            int idx = atomicAdd(&wsI[2], 1);
            int4 dsc;
            dsc.x = row * TT + s_pos[r];
            dsc.y = (int)c;
            dsc.z = __float_as_int(1.f / c);
            dsc.w = __float_as_int(1.f / rc);
            queue[idx] = dsc;
        }
    }

    // block-reduce vid
    #pragma unroll
    for (int off = 32; off >= 1; off >>= 1) vid += __shfl_xor(vid, off, 64);
    if (lane == 0) s_part[wv] = vid;
    __syncthreads();
    if (t == 0) {
        float tot = s_part[0] + s_part[1] + s_part[2] + s_part[3];
        atomicAdd(&wsF[0], tot / (float)max(nruns, 1));
    }
}

__global__ __launch_bounds__(256) void k_feat(const float* __restrict__ attn,
                                              const float* __restrict__ feat,
                                              const int4* __restrict__ queue,
                                              float* wsF, int* wsI,
                                              float* __restrict__ out) {
    __shared__ float s_part[4];
    const int lane = threadIdx.x & 63;
    const int wv   = threadIdx.x >> 6;
    const int wid  = blockIdx.x * 4 + wv;

    const int n = wsI[2];   // written by k_attn, visible across kernel boundary

    float s = 0.f;
    for (int item = wid; item < n; item += K2_WAVES) {
        const int4 d = queue[item];
        const float inv_cnt = __int_as_float(d.z);
        const float inv_rep = __int_as_float(d.w);
        float4 acc0 = {0, 0, 0, 0}, acc1 = {0, 0, 0, 0};
        for (int i = 0; i < d.y; i++) {
            const int p = d.x + i;
            const float av = attn[p];
            const float c = inv_cnt - (av > CT ? inv_rep : 0.f);
            const float4* f4 = (const float4*)(feat + (size_t)p * DD);
            float4 x = f4[lane];
            float4 y = f4[lane + 64];
            acc0.x += c * x.x; acc0.y += c * x.y; acc0.z += c * x.z; acc0.w += c * x.w;
            acc1.x += c * y.x; acc1.y += c * y.y; acc1.z += c * y.z; acc1.w += c * y.w;
        }
        s += acc0.x * acc0.x + acc0.y * acc0.y + acc0.z * acc0.z + acc0.w * acc0.w
           + acc1.x * acc1.x + acc1.y * acc1.y + acc1.z * acc1.z + acc1.w * acc1.w;
    }

    #pragma unroll
    for (int off = 32; off >= 1; off >>= 1) s += __shfl_xor(s, off, 64);
    if (lane == 0) s_part[wv] = s;
    __syncthreads();

    if (threadIdx.x == 0) {
        float b = s_part[0] + s_part[1] + s_part[2] + s_part[3];
        if (b != 0.f) atomicAdd(&wsF[1], b);
        __threadfence();
        int ticket = atomicAdd(&wsI[3], 1);
        if (ticket == (int)gridDim.x - 1) {
            // all blocks' adds are visible; coherent reads via atomic RMW
            float fa = atomicAdd(&wsF[1], 0.f);
            float aa = atomicAdd(&wsF[0], 0.f);
            out[0] = fa / (float)DD / (float)max(n, 1) + aa / (float)BB;
        }
    }
}

extern "C" void kernel_launch(void* const* d_in, const int* in_sizes, int n_in,
                              void* d_out, int out_size, void* d_ws, size_t ws_size,
                              hipStream_t stream) {
    const float* attn = (const float*)d_in[0];
    const float* feat = (const float*)d_in[1];
    float* wsF = (float*)d_ws;
    int*   wsI = (int*)d_ws;
    int4*  queue = (int4*)((char*)d_ws + 256);

    hipMemsetAsync(d_ws, 0, 256, stream);
    k_attn<<<BB, 256, 0, stream>>>(attn, queue, wsF, wsI);
    k_feat<<<K2_BLOCKS, 256, 0, stream>>>(attn, feat, queue, wsF, wsI, (float*)d_out);
}